// Round 1
// baseline (750.274 us; speedup 1.0000x reference)
//
#include <hip/hip_runtime.h>

// AdjacencyMatrix: G = softmax(theta @ phi^T) per (n,t), theta/phi = z @ W^T + b
// N=4 T=32 V=1024 C_IN=256 C_OUT=64.  NT=128 row-groups of 1024 rows.

#define LOG2E 1.44269504088896340736f

typedef float  floatx4 __attribute__((ext_vector_type(4)));
typedef short  shortx8 __attribute__((ext_vector_type(8)));

__device__ __forceinline__ unsigned short f2bf(float f) {
  unsigned int u = __builtin_bit_cast(unsigned int, f);
  u += 0x7fffu + ((u >> 16) & 1u);           // RNE
  return (unsigned short)(u >> 16);
}

__device__ __forceinline__ shortx8 load_cvt_bf16x8(const float* p) {
  float4 f0 = *(const float4*)p;
  float4 f1 = *(const float4*)(p + 4);
  shortx8 a;
  a[0] = (short)f2bf(f0.x); a[1] = (short)f2bf(f0.y);
  a[2] = (short)f2bf(f0.z); a[3] = (short)f2bf(f0.w);
  a[4] = (short)f2bf(f1.x); a[5] = (short)f2bf(f1.y);
  a[6] = (short)f2bf(f1.z); a[7] = (short)f2bf(f1.w);
  return a;
}

// ---------------------------------------------------------------------------
// Kernel 1: theta/phi projection. 1024 WGs x 256 thr; WG = 128 rows, 128 cols
// (cols 0..63 theta [pre-scaled by log2e], 64..127 phi). K=256 fully in LDS.
// MFMA 16x16x32_bf16: A m=lane&15, k=(lane>>4)*8+j ; C/D col=lane&15,
// row=(lane>>4)*4+reg (m89/m91-verified).
// ---------------------------------------------------------------------------
__global__ __launch_bounds__(256, 2)
void k_proj(const float* __restrict__ z,
            const float* __restrict__ tw, const float* __restrict__ tb,
            const float* __restrict__ pw, const float* __restrict__ pb,
            unsigned short* __restrict__ theta, unsigned short* __restrict__ phi)
{
  __shared__ unsigned short Wl[128 * 256];   // bf16 bits, XOR-swizzled k-groups
  const int tid  = threadIdx.x;
  const int lane = tid & 63;
  const int wv   = tid >> 6;
  const int c16  = lane & 15;
  const int q4   = lane >> 4;
  const size_t r0 = (size_t)blockIdx.x * 128;

  // stage concat[theta_w*log2e ; phi_w] -> LDS bf16 (swizzle: group g of row n
  // stored at group g^(n&31); 16B-aligned, conflict-free b128 reads)
  #pragma unroll
  for (int i = 0; i < 16; ++i) {
    int p = tid + i * 256;   // 0..4095 (row, k-group-of-8)
    int n = p >> 5;
    int g = p & 31;
    const float* src = (n < 64) ? (tw + (size_t)n * 256 + g * 8)
                                : (pw + (size_t)(n - 64) * 256 + g * 8);
    float sc = (n < 64) ? LOG2E : 1.0f;
    float4 f0 = *(const float4*)src;
    float4 f1 = *(const float4*)(src + 4);
    union { unsigned short h[8]; int4 v; } u;
    u.h[0] = f2bf(f0.x * sc); u.h[1] = f2bf(f0.y * sc);
    u.h[2] = f2bf(f0.z * sc); u.h[3] = f2bf(f0.w * sc);
    u.h[4] = f2bf(f1.x * sc); u.h[5] = f2bf(f1.y * sc);
    u.h[6] = f2bf(f1.z * sc); u.h[7] = f2bf(f1.w * sc);
    *(int4*)(&Wl[n * 256 + ((g ^ (n & 31)) * 8)]) = u.v;
  }
  __syncthreads();

  floatx4 acc[2][8];
  #pragma unroll
  for (int rt = 0; rt < 2; ++rt)
    #pragma unroll
    for (int ct = 0; ct < 8; ++ct) acc[rt][ct] = 0.0f;

  // wave rows: r0 + wv*32 + {rt*16 + (lane&15)}
  const float* z0 = z + (r0 + (size_t)wv * 32 + c16) * 256 + q4 * 8;
  #pragma unroll
  for (int s = 0; s < 8; ++s) {
    shortx8 a0 = load_cvt_bf16x8(z0 + s * 32);
    shortx8 a1 = load_cvt_bf16x8(z0 + 16 * 256 + s * 32);
    #pragma unroll
    for (int ct = 0; ct < 8; ++ct) {
      int n = ct * 16 + c16;
      int g = s * 4 + q4;
      shortx8 b = *(const shortx8*)(&Wl[n * 256 + ((g ^ (n & 31)) * 8)]);
      acc[0][ct] = __builtin_amdgcn_mfma_f32_16x16x32_bf16(a0, b, acc[0][ct], 0, 0, 0);
      acc[1][ct] = __builtin_amdgcn_mfma_f32_16x16x32_bf16(a1, b, acc[1][ct], 0, 0, 0);
    }
  }

  // epilogue: bias (theta bias pre-scaled by log2e), store bf16 row-major [row][64]
  #pragma unroll
  for (int ct = 0; ct < 8; ++ct) {
    int c = ct * 16 + c16;
    float bias = (c < 64) ? tb[c] * LOG2E : pb[c - 64];
    #pragma unroll
    for (int rt = 0; rt < 2; ++rt)
      #pragma unroll
      for (int r = 0; r < 4; ++r) {
        size_t gr = r0 + (size_t)wv * 32 + rt * 16 + q4 * 4 + r;
        unsigned short hv = f2bf(acc[rt][ct][r] + bias);
        if (c < 64) theta[gr * 64 + c] = hv;
        else        phi[gr * 64 + (c - 64)] = hv;
      }
  }
}

// ---------------------------------------------------------------------------
// Kernel 2: S = theta.phi^T + row softmax + write G.
// 4096 WGs (nt 0..127 x 32-row block), 256 thr = 4 waves.
// Wave wv: 32 rows x cols [wv*256, wv*256+256): 2 row-tiles x 16 col-tiles,
// K=64 in 2 MFMA steps. acc = 128 VGPR. Fragments streamed from L1/L2
// (phi per nt = 128 KiB, LLC-resident). theta pre-scaled by log2e -> exp2.
// ---------------------------------------------------------------------------
__global__ __launch_bounds__(256, 2)
void k_adj(const unsigned short* __restrict__ theta,
           const unsigned short* __restrict__ phi,
           float* __restrict__ out)
{
  __shared__ __align__(16) float redm[32][4];
  __shared__ __align__(16) float reds[32][4];
  const int tid  = threadIdx.x;
  const int lane = tid & 63;
  const int wv   = tid >> 6;
  const int c16  = lane & 15;
  const int q4   = lane >> 4;
  const int nt   = blockIdx.x >> 5;
  const int vb   = blockIdx.x & 31;

  const unsigned short* tbase =
      theta + ((size_t)nt * 1024 + vb * 32 + c16) * 64 + q4 * 8;
  const unsigned short* pbase =
      phi + ((size_t)nt * 1024 + wv * 256 + c16) * 64 + q4 * 8;

  floatx4 acc[2][16];
  #pragma unroll
  for (int rt = 0; rt < 2; ++rt)
    #pragma unroll
    for (int ct = 0; ct < 16; ++ct) acc[rt][ct] = 0.0f;

  #pragma unroll
  for (int s = 0; s < 2; ++s) {
    shortx8 a0 = *(const shortx8*)(tbase + s * 32);
    shortx8 a1 = *(const shortx8*)(tbase + 16 * 64 + s * 32);
    #pragma unroll
    for (int ct = 0; ct < 16; ++ct) {
      shortx8 b = *(const shortx8*)(pbase + (size_t)ct * 16 * 64 + s * 32);
      acc[0][ct] = __builtin_amdgcn_mfma_f32_16x16x32_bf16(a0, b, acc[0][ct], 0, 0, 0);
      acc[1][ct] = __builtin_amdgcn_mfma_f32_16x16x32_bf16(a1, b, acc[1][ct], 0, 0, 0);
    }
  }

  // ---- softmax over 1024 cols (per-wave 256 + cross-wave combine) ----
  // lane holds rows {rt*16 + q4*4 + r}; cols {ct*16 + c16}. Row groups = 16
  // lanes with equal q4 -> shfl_xor masks 1,2,4,8 stay in-group.
  float rmax[2][4];
  #pragma unroll
  for (int rt = 0; rt < 2; ++rt)
    #pragma unroll
    for (int r = 0; r < 4; ++r) {
      float m = acc[rt][0][r];
      #pragma unroll
      for (int ct = 1; ct < 16; ++ct) m = fmaxf(m, acc[rt][ct][r]);
      rmax[rt][r] = m;
    }
  #pragma unroll
  for (int mask = 1; mask <= 8; mask <<= 1)
    #pragma unroll
    for (int rt = 0; rt < 2; ++rt)
      #pragma unroll
      for (int r = 0; r < 4; ++r)
        rmax[rt][r] = fmaxf(rmax[rt][r], __shfl_xor(rmax[rt][r], mask, 64));

  if (c16 == 0) {
    #pragma unroll
    for (int rt = 0; rt < 2; ++rt)
      #pragma unroll
      for (int r = 0; r < 4; ++r)
        redm[rt * 16 + q4 * 4 + r][wv] = rmax[rt][r];
  }
  __syncthreads();

  float gmax[2][4], rsum[2][4];
  #pragma unroll
  for (int rt = 0; rt < 2; ++rt)
    #pragma unroll
    for (int r = 0; r < 4; ++r) {
      float4 v = *(const float4*)(&redm[rt * 16 + q4 * 4 + r][0]);
      gmax[rt][r] = fmaxf(fmaxf(v.x, v.y), fmaxf(v.z, v.w));
      rsum[rt][r] = 0.0f;
    }

  // exp2 with the GLOBAL max (theta pre-scaled by log2e) -> partial sums add plainly
  #pragma unroll
  for (int rt = 0; rt < 2; ++rt)
    #pragma unroll
    for (int ct = 0; ct < 16; ++ct)
      #pragma unroll
      for (int r = 0; r < 4; ++r) {
        float e = exp2f(acc[rt][ct][r] - gmax[rt][r]);
        acc[rt][ct][r] = e;
        rsum[rt][r] += e;
      }
  #pragma unroll
  for (int mask = 1; mask <= 8; mask <<= 1)
    #pragma unroll
    for (int rt = 0; rt < 2; ++rt)
      #pragma unroll
      for (int r = 0; r < 4; ++r)
        rsum[rt][r] += __shfl_xor(rsum[rt][r], mask, 64);

  if (c16 == 0) {
    #pragma unroll
    for (int rt = 0; rt < 2; ++rt)
      #pragma unroll
      for (int r = 0; r < 4; ++r)
        reds[rt * 16 + q4 * 4 + r][wv] = rsum[rt][r];
  }
  __syncthreads();

  float rinv[2][4];
  #pragma unroll
  for (int rt = 0; rt < 2; ++rt)
    #pragma unroll
    for (int r = 0; r < 4; ++r) {
      float4 v = *(const float4*)(&reds[rt * 16 + q4 * 4 + r][0]);
      rinv[rt][r] = __builtin_amdgcn_rcpf(v.x + v.y + v.z + v.w);
    }

  float* ob = out + (size_t)nt * 1024 * 1024 + (size_t)vb * 32 * 1024
                  + wv * 256 + c16;
  #pragma unroll
  for (int rt = 0; rt < 2; ++rt)
    #pragma unroll
    for (int r = 0; r < 4; ++r) {
      float* orow = ob + (size_t)(rt * 16 + q4 * 4 + r) * 1024;
      float sc = rinv[rt][r];
      #pragma unroll
      for (int ct = 0; ct < 16; ++ct)
        orow[ct * 16] = acc[rt][ct][r] * sc;
    }
}

// ---------------------------------------------------------------------------
extern "C" void kernel_launch(void* const* d_in, const int* in_sizes, int n_in,
                              void* d_out, int out_size, void* d_ws, size_t ws_size,
                              hipStream_t stream) {
  const float* z  = (const float*)d_in[0];
  const float* tw = (const float*)d_in[1];
  const float* tb = (const float*)d_in[2];
  const float* pw = (const float*)d_in[3];
  const float* pb = (const float*)d_in[4];
  float* out = (float*)d_out;

  unsigned short* theta = (unsigned short*)d_ws;                    // 16 MiB
  unsigned short* phi   = theta + (size_t)131072 * 64;              // +16 MiB

  k_proj<<<dim3(1024), dim3(256), 0, stream>>>(z, tw, tb, pw, pb, theta, phi);
  k_adj<<<dim3(4096), dim3(256), 0, stream>>>(theta, phi, out);
}